// Round 2
// baseline (2741.807 us; speedup 1.0000x reference)
//
// R2: same design as R1 (persistent per-tile MFMA scan), resubmitted after a
// full desk audit — R0/R1 both failed on GPU acquisition, so there is no
// counter evidence to act on. Audit covered: MFMA A/B/C/D layouts per
// m74/m101, buildfr permlane element mapping, swizzle write/read consistency
// (rule 21: linear global_load_lds dest + pre-swizzled source), barrier/race
// analysis, K-ext bias algebra, ~440 VGPR budget (<512 @ launch_bounds 256,1).
// Structure: 1024 blocks x 256 thr; each block owns 128 rows, iterates all
// 128 scan steps locally (rows independent across blocks -> no global sync).
// All GEMMs computed transposed (D' = W * act^T) so activations flow
// register->register via v_cvt_pk_bf16_f32 + permlane32_swap (no LDS bounce).
// Per-step Wx staged via global_load_lds from a pre-swizzled bf16 image in ws.
// K extended 128->144 to fold z*wz + bi (L1) and b1/b2 (L2/L3) into MFMA.
// Predicted: ~1ms, MfmaUtil 50-75%, near-zero LDS bank conflicts.

#include <hip/hip_runtime.h>
#include <hip/hip_bf16.h>

typedef __bf16 bf16x8 __attribute__((ext_vector_type(8)));
typedef float  f32x16 __attribute__((ext_vector_type(16)));

#define AS1 __attribute__((address_space(1)))
#define AS3 __attribute__((address_space(3)))

#define NROWS 131072u
#define TM    128u

// ---------- helpers ----------
static __device__ __forceinline__ unsigned short bf16r(float x){ // RNE f32->bf16
  unsigned u = __builtin_bit_cast(unsigned, x);
  u = (u + 0x7FFFu + ((u >> 16) & 1u)) >> 16;
  return (unsigned short)u;
}
static __device__ __forceinline__ unsigned pk2c(float lo, float hi){
  unsigned d;
  asm("v_cvt_pk_bf16_f32 %0, %1, %2" : "=v"(d) : "v"(lo), "v"(hi));
  return d; // lo16 = bf16(lo), hi16 = bf16(hi)
}
static __device__ __forceinline__ bf16x8 mkfrag(unsigned a, unsigned b, unsigned c, unsigned d){
  uint4 t; t.x = a; t.y = b; t.z = c; t.w = d;
  return __builtin_bit_cast(bf16x8, t);
}
static __device__ __forceinline__ bf16x8 ldfrag(const unsigned short* base, unsigned byteoff){
  const uint4 v = *(const uint4*)((const char*)base + byteoff);
  return __builtin_bit_cast(bf16x8, v);
}
static __device__ __forceinline__ f32x16 zero16(){
  f32x16 v;
  #pragma unroll
  for (int j = 0; j < 16; ++j) v[j] = 0.0f;
  return v;
}
static __device__ __forceinline__ void relu16(f32x16& a){
  #pragma unroll
  for (int j = 0; j < 16; ++j) a[j] = fmaxf(a[j], 0.0f);
}
// Build B-frags (2 k-windows) for the next transposed GEMM from a relu'd acc
// tile. D-layout: col=lane&31, row nu=(r&3)+8*(r>>2)+4*(lane>>5)  [m74/m101].
// B-frag needs 8 consecutive k at own col; missing nu's live at lane^32 ->
// permlane32_swap: {B0,B2}=swap(pk(a0,a1),pk(a4,a5)), {B1,B3}=swap(pk(a2,a3),pk(a6,a7)).
static __device__ __forceinline__ void buildfr(const f32x16& a, unsigned lo[4], unsigned hi[4]){
  unsigned p0 = pk2c(a[0],a[1]),  p1 = pk2c(a[2],a[3]);
  unsigned p2 = pk2c(a[4],a[5]),  p3 = pk2c(a[6],a[7]);
  unsigned q0 = pk2c(a[8],a[9]),  q1 = pk2c(a[10],a[11]);
  unsigned q2 = pk2c(a[12],a[13]),q3 = pk2c(a[14],a[15]);
  { auto r = __builtin_amdgcn_permlane32_swap(p0, p2, false, false); lo[0]=r[0]; lo[2]=r[1]; }
  { auto r = __builtin_amdgcn_permlane32_swap(p1, p3, false, false); lo[1]=r[0]; lo[3]=r[1]; }
  { auto r = __builtin_amdgcn_permlane32_swap(q0, q2, false, false); hi[0]=r[0]; hi[2]=r[1]; }
  { auto r = __builtin_amdgcn_permlane32_swap(q1, q3, false, false); hi[1]=r[0]; hi[3]=r[1]; }
}
// Stage the 32KB pre-swizzled Wx image for step i into LDS (linear copy).
static __device__ __forceinline__ void stage(const unsigned short* __restrict__ wxp,
                                             unsigned short* wx_lds,
                                             unsigned i, unsigned wid, unsigned lane){
  const char* src = (const char*)wxp + (size_t)i*32768u + wid*8192u + lane*16u;
  char* dst = (char*)wx_lds + wid*8192u;            // wave-uniform base; HW adds lane*16
  #pragma unroll
  for (unsigned c = 0; c < 8; ++c)
    __builtin_amdgcn_global_load_lds((const AS1 unsigned*)(src + c*1024u),
                                     (AS3 unsigned*)(dst + c*1024u), 16, 0, 0);
}

// ---------- prep kernels (run every launch; all cheap) ----------
// wxp[i] = bf16( Wi[i,hh,j] * mask_i[j] ), stored as the exact 32KB swizzled
// LDS image (slot ^= row&15 within each 256B row). ext_img[i][m] = {wz, bi}.
__global__ __launch_bounds__(256) void prep_w(const float* __restrict__ Wi,
                                              const float* __restrict__ M,
                                              const float* __restrict__ bi,
                                              unsigned short* __restrict__ wxp,
                                              unsigned* __restrict__ extimg){
  const unsigned i = blockIdx.x, tid = threadIdx.x;
  __shared__ float mcol[128];
  if (tid < 128u) mcol[tid] = (tid == i) ? 0.0f : M[tid*128u + i];
  __syncthreads();
  const float* wrow = Wi + (size_t)i*128u*129u;
  unsigned short* dst = wxp + (size_t)i*16384u;
  #pragma unroll 4
  for (unsigned p = 0; p < 64; ++p){
    unsigned e = p*256u + tid;
    unsigned hh = e >> 7, j = e & 127u;
    float v = wrow[hh*129u + j] * mcol[j];
    dst[hh*128u + ((((j>>3) ^ (hh & 15u)) << 3) | (j & 7u))] = bf16r(v);
  }
  if (tid < 128u){
    float wz = wrow[tid*129u + 128u];
    float bv = bi[i*128u + tid];
    extimg[i*128u + tid] = (unsigned)bf16r(wz) | ((unsigned)bf16r(bv) << 16);
  }
}
// zT[i][b] = bf16(z[b][i])  (coalesced transpose through LDS)
__global__ __launch_bounds__(256) void prep_z(const float* __restrict__ z,
                                              unsigned short* __restrict__ zT){
  __shared__ float t[64][129];
  const unsigned tid = threadIdx.x, b0 = blockIdx.x * 64u;
  #pragma unroll 4
  for (unsigned p = 0; p < 32; ++p){
    unsigned e = p*256u + tid;
    t[e >> 7][e & 127u] = z[(size_t)b0*128u + e];
  }
  __syncthreads();
  #pragma unroll 4
  for (unsigned p = 0; p < 32; ++p){
    unsigned e = p*256u + tid;
    unsigned ii = e >> 6, bb = e & 63u;
    zT[(size_t)ii*NROWS + b0 + bb] = bf16r(t[bb][ii]);
  }
}

// ---------- main persistent scan kernel ----------
__global__ __launch_bounds__(256, 1) void gen_main(
    const float* __restrict__ x,   const float* __restrict__ Wf,
    const float* __restrict__ bfp, const float* __restrict__ W1,
    const float* __restrict__ b1,  const float* __restrict__ W2,
    const float* __restrict__ b2,  const unsigned short* __restrict__ wxp,
    const unsigned* __restrict__ extimg, const unsigned short* __restrict__ zT,
    float* __restrict__ out)
{
  __shared__ unsigned short o_lds[16384];   // out state, bf16, swizzled
  __shared__ unsigned short wx_lds[16384];  // per-step Wx image
  __shared__ float wf_lds[128];             // Wf[i] permuted to [mu][r][h]

  const unsigned tid  = threadIdx.x;
  const unsigned wid  = tid >> 6, lane = tid & 63u;
  const unsigned l31  = lane & 31u, hf = lane >> 5;
  const unsigned r0   = blockIdx.x * TM;
  const unsigned strip = wid * 32u;

  // out_lds <- bf16(x) (swizzled)
  #pragma unroll 4
  for (unsigned p = 0; p < 64; ++p){
    unsigned e = p*256u + tid;
    unsigned row = e >> 7, col = e & 127u;
    float v = x[(size_t)r0*128u + e];
    o_lds[row*128u + ((((col>>3) ^ (row & 15u)) << 3) | (col & 7u))] = bf16r(v);
  }

  // W1/W2 A-fragments resident in VGPRs (+ K-ext frag carrying b1/b2)
  bf16x8 w1f[4][9], w2f[4][9];
  #pragma unroll
  for (unsigned mu = 0; mu < 4; ++mu){
    const unsigned row = mu*32u + l31;
    #pragma unroll
    for (unsigned w = 0; w < 8; ++w){
      const float4 a0 = *(const float4*)(W1 + row*128u + w*16u + hf*8u);
      const float4 a1 = *(const float4*)(W1 + row*128u + w*16u + hf*8u + 4u);
      w1f[mu][w] = mkfrag(pk2c(a0.x,a0.y), pk2c(a0.z,a0.w), pk2c(a1.x,a1.y), pk2c(a1.z,a1.w));
      const float4 c0 = *(const float4*)(W2 + row*128u + w*16u + hf*8u);
      const float4 c1 = *(const float4*)(W2 + row*128u + w*16u + hf*8u + 4u);
      w2f[mu][w] = mkfrag(pk2c(c0.x,c0.y), pk2c(c0.z,c0.w), pk2c(c1.x,c1.y), pk2c(c1.z,c1.w));
    }
    w1f[mu][8] = mkfrag(hf==0u ? (unsigned)bf16r(b1[row]) : 0u, 0u, 0u, 0u);
    w2f[mu][8] = mkfrag(hf==0u ? (unsigned)bf16r(b2[row]) : 0u, 0u, 0u, 0u);
  }

  // swizzled byte offsets: byte-in-row slot (2w+hf), XOR row&15
  unsigned offw[8];
  #pragma unroll
  for (unsigned w = 0; w < 8; ++w) offw[w] = ((2u*w + hf) ^ (l31 & 15u)) << 4;
  unsigned rowA[4];
  #pragma unroll
  for (unsigned mu = 0; mu < 4; ++mu) rowA[mu] = (mu*32u + l31) * 256u;
  const unsigned rowB = (strip + l31) * 256u;

  stage(wxp, wx_lds, 0u, wid, lane);
  __syncthreads();

  #pragma unroll 1
  for (unsigned i = 0; i < 128u; ++i){
    // per-step small loads (latency hidden under L1)
    if (tid < 128u){ // Wf[i] -> [mu][r][h] table for the epilogue
      float v = Wf[i*128u + tid];
      unsigned nu = tid & 31u, mm = tid >> 5;
      unsigned hb = (nu >> 2) & 1u, rr = (nu & 3u) | ((nu >> 3) << 2);
      wf_lds[mm*32u + rr*2u + hb] = v;
    }
    const unsigned short zb = zT[(size_t)i*NROWS + r0 + strip + l31];
    const unsigned eB = (hf == 0u) ? ((unsigned)zb | 0x3F800000u) : 0u; // {z_b, 1.0}
    unsigned ea[4];
    #pragma unroll
    for (unsigned mu = 0; mu < 4; ++mu)
      ea[mu] = (hf == 0u) ? extimg[i*128u + mu*32u + l31] : 0u;          // {wz, bi}
    const float bfi = bfp[i];

    // ---- L1: D1'[hh][b] = sum_j Wx'[hh][j] * out[b][j]  (+ ext k=128,129) ----
    f32x16 a1[4];
    #pragma unroll
    for (unsigned mu = 0; mu < 4; ++mu) a1[mu] = zero16();
    #pragma unroll
    for (unsigned w = 0; w < 8; ++w){
      const bf16x8 bfr = ldfrag(o_lds, rowB + offw[w]);
      #pragma unroll
      for (unsigned mu = 0; mu < 4; ++mu)
        a1[mu] = __builtin_amdgcn_mfma_f32_32x32x16_bf16(
                   ldfrag(wx_lds, rowA[mu] + offw[w]), bfr, a1[mu], 0, 0, 0);
    }
    {
      const bf16x8 be = mkfrag(eB, 0u, 0u, 0u);
      #pragma unroll
      for (unsigned mu = 0; mu < 4; ++mu)
        a1[mu] = __builtin_amdgcn_mfma_f32_32x32x16_bf16(
                   mkfrag(ea[mu], 0u, 0u, 0u), be, a1[mu], 0, 0, 0);
    }

    __syncthreads();                       // all waves done reading wx_lds(i)
    if (i + 1u < 128u) stage(wxp, wx_lds, i + 1u, wid, lane); // async prefetch

    // ---- h1 -> register B-frags ----
    unsigned fr[9][4];
    #pragma unroll
    for (unsigned mu = 0; mu < 4; ++mu){
      relu16(a1[mu]);
      buildfr(a1[mu], fr[2u*mu], fr[2u*mu+1u]);
    }
    fr[8][0] = (hf == 0u) ? 0x00003F80u : 0u;  // virtual act row 128 = 1.0 (for b1)
    fr[8][1] = fr[8][2] = fr[8][3] = 0u;

    // ---- L2: D2'[n2][b] = W1 * h1^T  (+ b1 via ext) ----
    f32x16 a2[4];
    #pragma unroll
    for (unsigned mu = 0; mu < 4; ++mu) a2[mu] = zero16();
    #pragma unroll
    for (unsigned w = 0; w < 9; ++w){
      const bf16x8 bb = mkfrag(fr[w][0], fr[w][1], fr[w][2], fr[w][3]);
      #pragma unroll
      for (unsigned mu = 0; mu < 4; ++mu)
        a2[mu] = __builtin_amdgcn_mfma_f32_32x32x16_bf16(w1f[mu][w], bb, a2[mu], 0, 0, 0);
    }

    // ---- h2 -> frags ----
    #pragma unroll
    for (unsigned mu = 0; mu < 4; ++mu){
      relu16(a2[mu]);
      buildfr(a2[mu], fr[2u*mu], fr[2u*mu+1u]);
    }
    fr[8][0] = (hf == 0u) ? 0x00003F80u : 0u;
    fr[8][1] = fr[8][2] = fr[8][3] = 0u;

    // ---- L3: D3'[n3][b] = W2 * h2^T  (+ b2 via ext) ----
    f32x16 a3[4];
    #pragma unroll
    for (unsigned mu = 0; mu < 4; ++mu) a3[mu] = zero16();
    #pragma unroll
    for (unsigned w = 0; w < 9; ++w){
      const bf16x8 bb = mkfrag(fr[w][0], fr[w][1], fr[w][2], fr[w][3]);
      #pragma unroll
      for (unsigned mu = 0; mu < 4; ++mu)
        a3[mu] = __builtin_amdgcn_mfma_f32_32x32x16_bf16(w2f[mu][w], bb, a3[mu], 0, 0, 0);
    }

    // ---- epilogue: o[b] = sum_n3 relu(D3'[n3][b]) * Wf[i][n3] + bf[i] ----
    float s = 0.0f;
    #pragma unroll
    for (unsigned mu = 0; mu < 4; ++mu){
      #pragma unroll
      for (unsigned r = 0; r < 16; ++r){
        const float2 wp = *(const float2*)(&wf_lds[mu*32u + r*2u]); // broadcast
        s += fmaxf(a3[mu][r], 0.0f) * (hf ? wp.y : wp.x);
      }
    }
    s += __shfl_xor(s, 32, 64);            // combine the two half-wave row sets
    const float o = s + bfi;
    if (hf == 0u){
      const unsigned row = strip + l31;
      o_lds[row*128u + ((((i>>3) ^ (l31 & 15u)) << 3) | (i & 7u))] = bf16r(o);
      out[(size_t)(r0 + row)*128u + i] = o;
    }
    __syncthreads();                       // drains staging vmcnt; col-i visible
  }
}

// ---------- host ----------
extern "C" void kernel_launch(void* const* d_in, const int* in_sizes, int n_in,
                              void* d_out, int out_size, void* d_ws, size_t ws_size,
                              hipStream_t stream) {
  (void)in_sizes; (void)n_in; (void)out_size;
  const float* x  = (const float*)d_in[0];
  const float* z  = (const float*)d_in[1];
  const float* M  = (const float*)d_in[2];
  const float* Wi = (const float*)d_in[3];
  const float* bi = (const float*)d_in[4];
  const float* Wf = (const float*)d_in[5];
  const float* bf = (const float*)d_in[6];
  const float* W1 = (const float*)d_in[7];
  const float* b1 = (const float*)d_in[8];
  const float* W2 = (const float*)d_in[9];
  const float* b2 = (const float*)d_in[10];
  float* out = (float*)d_out;

  // ws layout: wxp 4MB | ext_img 64KB | zT 32MB  (total ~36.1MB)
  char* ws = (char*)d_ws;
  unsigned short* wxp    = (unsigned short*)ws;
  unsigned*       extimg = (unsigned*)(ws + 4194304u);
  unsigned short* zTp    = (unsigned short*)(ws + 4194304u + 65536u);
  (void)ws_size; // requires ws_size >= 37,814,272 bytes

  prep_w<<<128, 256, 0, stream>>>(Wi, M, bi, wxp, extimg);
  prep_z<<<NROWS/64u, 256, 0, stream>>>(z, zTp);
  gen_main<<<NROWS/TM, 256, 0, stream>>>(x, Wf, bf, W1, b1, W2, b2,
                                         wxp, extimg, zTp, out);
}

// Round 4
// 2447.147 us; speedup vs baseline: 1.1204x; 1.1204x over previous
//
// R4 = R3 resubmitted (GPU acquisition failed; no evidence to act on).
// Desk audit this round: race matrix across B1/B2/Bp/B3, kpair->C/D-row
// mapping, h-LDS write/read swizzle agreement (bcol&15==l31&15), write bank
// pattern (16 banks x 2-way = free), wf_s permutation inverse, K-ext algebra,
// ~240 VGPR < 256 cap, LDS 129.5KB -> 1 block/CU = 2 waves/SIMD.
// Structure: 512 thr = 8 waves = (2 r) x (4 c); wave (r,c) computes h-rows
// [64r,64r+64) x batch-cols [32c,32c+32). Weights per wave: 148 regs. Layer
// handoff h1/h2 via swizzled bf16 LDS buffers; final dot reduced across the
// r-pair via a small LDS partial buffer. 4 barriers/step.
// Predicted vs R2 baseline (2900us/28%/12.1%): 1000-1400us, Occupancy ~25%,
// MfmaUtil 45-60%, WRITE ~110MB (spill-write diagnostic).

#include <hip/hip_runtime.h>
#include <hip/hip_bf16.h>

typedef __bf16 bf16x8 __attribute__((ext_vector_type(8)));
typedef float  f32x16 __attribute__((ext_vector_type(16)));

#define AS1 __attribute__((address_space(1)))
#define AS3 __attribute__((address_space(3)))

#define NROWS 131072u
#define TM    128u

// ---------- helpers ----------
static __device__ __forceinline__ unsigned short bf16r(float x){ // RNE f32->bf16
  unsigned u = __builtin_bit_cast(unsigned, x);
  u = (u + 0x7FFFu + ((u >> 16) & 1u)) >> 16;
  return (unsigned short)u;
}
static __device__ __forceinline__ unsigned pk2c(float lo, float hi){
  unsigned d;
  asm("v_cvt_pk_bf16_f32 %0, %1, %2" : "=v"(d) : "v"(lo), "v"(hi));
  return d; // lo16 = bf16(lo), hi16 = bf16(hi)
}
static __device__ __forceinline__ bf16x8 mkfrag(unsigned a, unsigned b, unsigned c, unsigned d){
  uint4 t; t.x = a; t.y = b; t.z = c; t.w = d;
  return __builtin_bit_cast(bf16x8, t);
}
static __device__ __forceinline__ bf16x8 ldfrag(const unsigned short* base, unsigned byteoff){
  const uint4 v = *(const uint4*)((const char*)base + byteoff);
  return __builtin_bit_cast(bf16x8, v);
}
static __device__ __forceinline__ f32x16 zero16(){
  f32x16 v;
  #pragma unroll
  for (int j = 0; j < 16; ++j) v[j] = 0.0f;
  return v;
}
static __device__ __forceinline__ void relu16(f32x16& a){
  #pragma unroll
  for (int j = 0; j < 16; ++j) a[j] = fmaxf(a[j], 0.0f);
}
// Stage the 32KB pre-swizzled Wx image for step i into LDS (linear copy, 8 waves).
static __device__ __forceinline__ void stage(const unsigned short* __restrict__ wxp,
                                             unsigned short* wx_lds,
                                             unsigned i, unsigned wid, unsigned lane){
  const char* src = (const char*)wxp + (size_t)i*32768u + wid*4096u + lane*16u;
  char* dst = (char*)wx_lds + wid*4096u;            // wave-uniform base; HW adds lane*16
  #pragma unroll
  for (unsigned c = 0; c < 4; ++c)
    __builtin_amdgcn_global_load_lds((const AS1 unsigned*)(src + c*1024u),
                                     (AS3 unsigned*)(dst + c*1024u), 16, 0, 0);
}

// ---------- prep kernels ----------
__global__ __launch_bounds__(256) void prep_w(const float* __restrict__ Wi,
                                              const float* __restrict__ M,
                                              const float* __restrict__ bi,
                                              unsigned short* __restrict__ wxp,
                                              unsigned* __restrict__ extimg){
  const unsigned i = blockIdx.x, tid = threadIdx.x;
  __shared__ float mcol[128];
  if (tid < 128u) mcol[tid] = (tid == i) ? 0.0f : M[tid*128u + i];
  __syncthreads();
  const float* wrow = Wi + (size_t)i*128u*129u;
  unsigned short* dst = wxp + (size_t)i*16384u;
  #pragma unroll 4
  for (unsigned p = 0; p < 64; ++p){
    unsigned e = p*256u + tid;
    unsigned hh = e >> 7, j = e & 127u;
    float v = wrow[hh*129u + j] * mcol[j];
    dst[hh*128u + ((((j>>3) ^ (hh & 15u)) << 3) | (j & 7u))] = bf16r(v);
  }
  if (tid < 128u){
    float wz = wrow[tid*129u + 128u];
    float bv = bi[i*128u + tid];
    extimg[i*128u + tid] = (unsigned)bf16r(wz) | ((unsigned)bf16r(bv) << 16);
  }
}
__global__ __launch_bounds__(256) void prep_z(const float* __restrict__ z,
                                              unsigned short* __restrict__ zT){
  __shared__ float t[64][129];
  const unsigned tid = threadIdx.x, b0 = blockIdx.x * 64u;
  #pragma unroll 4
  for (unsigned p = 0; p < 32; ++p){
    unsigned e = p*256u + tid;
    t[e >> 7][e & 127u] = z[(size_t)b0*128u + e];
  }
  __syncthreads();
  #pragma unroll 4
  for (unsigned p = 0; p < 32; ++p){
    unsigned e = p*256u + tid;
    unsigned ii = e >> 6, bb = e & 63u;
    zT[(size_t)ii*NROWS + b0 + bb] = bf16r(t[bb][ii]);
  }
}

// ---------- main persistent scan kernel ----------
__global__ __launch_bounds__(512, 2) void gen_main(
    const float* __restrict__ x,   const float* __restrict__ Wf,
    const float* __restrict__ bfp, const float* __restrict__ W1,
    const float* __restrict__ b1,  const float* __restrict__ W2,
    const float* __restrict__ b2,  const unsigned short* __restrict__ wxp,
    const unsigned* __restrict__ extimg, const unsigned short* __restrict__ zT,
    float* __restrict__ out)
{
  __shared__ unsigned short o_lds[16384];   // out state [b][j], bf16, swizzled
  __shared__ unsigned short wx_lds[16384];  // per-step Wx image
  __shared__ unsigned short h1_lds[16384];  // [b][k] bf16, swizzled
  __shared__ unsigned short h2_lds[16384];  // [b][k] bf16, swizzled
  __shared__ float wf_s[128];               // Wf[i] in [mu][hf][reg] order
  __shared__ float part_s[256];             // [r][b] epilogue partials

  const unsigned tid  = threadIdx.x;
  const unsigned wid  = tid >> 6, lane = tid & 63u;
  const unsigned l31  = lane & 31u, hf = lane >> 5;
  const unsigned rr_  = wid >> 2, cc_ = wid & 3u;   // h-row pair / batch-col group
  const unsigned r0   = blockIdx.x * TM;
  const unsigned bcol = cc_*32u + l31;              // owned batch row/col

  // o_lds <- bf16(x) (swizzled)
  #pragma unroll 4
  for (unsigned p = 0; p < 32; ++p){
    unsigned e = p*512u + tid;
    unsigned row = e >> 7, col = e & 127u;
    float v = x[(size_t)r0*128u + e];
    o_lds[row*128u + ((((col>>3) ^ (row & 15u)) << 3) | (col & 7u))] = bf16r(v);
  }

  // Per-wave weight slices: rows [64r+32m+l31], k-window w (+ K-ext bias frag)
  bf16x8 w1f[2][9], w2f[2][9];
  #pragma unroll
  for (unsigned m = 0; m < 2; ++m){
    const unsigned row = rr_*64u + m*32u + l31;
    #pragma unroll
    for (unsigned w = 0; w < 8; ++w){
      const float4 a0 = *(const float4*)(W1 + row*128u + w*16u + hf*8u);
      const float4 a1 = *(const float4*)(W1 + row*128u + w*16u + hf*8u + 4u);
      w1f[m][w] = mkfrag(pk2c(a0.x,a0.y), pk2c(a0.z,a0.w), pk2c(a1.x,a1.y), pk2c(a1.z,a1.w));
      const float4 c0 = *(const float4*)(W2 + row*128u + w*16u + hf*8u);
      const float4 c1 = *(const float4*)(W2 + row*128u + w*16u + hf*8u + 4u);
      w2f[m][w] = mkfrag(pk2c(c0.x,c0.y), pk2c(c0.z,c0.w), pk2c(c1.x,c1.y), pk2c(c1.z,c1.w));
    }
    w1f[m][8] = mkfrag(hf==0u ? (unsigned)bf16r(b1[row]) : 0u, 0u, 0u, 0u);
    w2f[m][8] = mkfrag(hf==0u ? (unsigned)bf16r(b2[row]) : 0u, 0u, 0u, 0u);
  }
  const bf16x8 frext = mkfrag(hf==0u ? 0x00003F80u : 0u, 0u, 0u, 0u); // act=1.0 @k-ext0

  unsigned offw[8];
  #pragma unroll
  for (unsigned w = 0; w < 8; ++w) offw[w] = ((2u*w + hf) ^ (l31 & 15u)) << 4;
  unsigned rowA[2];
  #pragma unroll
  for (unsigned m = 0; m < 2; ++m) rowA[m] = (rr_*64u + m*32u + l31) * 256u;
  const unsigned rowB = bcol * 256u;
  const unsigned kpair[8] = {0u,2u,8u,10u,16u,18u,24u,26u}; // acc reg-pair -> k offset

  stage(wxp, wx_lds, 0u, wid, lane);
  __syncthreads();

  #pragma unroll 1
  for (unsigned i = 0; i < 128u; ++i){
    if (tid < 128u){ // Wf[i] -> [mu][hf][reg] table (read post-L3; B1/B2 intervene)
      unsigned mu = tid >> 5, rem = tid & 31u;
      unsigned hfv = (rem >> 2) & 1u, rg = (rem & 3u) | ((rem >> 3) << 2);
      wf_s[mu*32u + hfv*16u + rg] = Wf[i*128u + tid];
    }
    const unsigned short zb = zT[(size_t)i*NROWS + r0 + bcol];
    const unsigned eB = (hf == 0u) ? ((unsigned)zb | 0x3F800000u) : 0u;   // {z, 1.0}
    unsigned ea[2];
    #pragma unroll
    for (unsigned m = 0; m < 2; ++m)
      ea[m] = (hf == 0u) ? extimg[i*128u + rr_*64u + m*32u + l31] : 0u;   // {wz, bi}
    const float bfi = bfp[i];

    // ---- L1: D1'[h][b] = Wx' * out^T (+ z*wz + bi via K-ext) ----
    f32x16 acc[2];
    {
      const bf16x8 be = mkfrag(eB, 0u, 0u, 0u);
      #pragma unroll
      for (unsigned m = 0; m < 2; ++m)
        acc[m] = __builtin_amdgcn_mfma_f32_32x32x16_bf16(
                   mkfrag(ea[m],0u,0u,0u), be, zero16(), 0, 0, 0);
    }
    #pragma unroll
    for (unsigned w = 0; w < 8; ++w){
      const bf16x8 bo = ldfrag(o_lds, rowB + offw[w]);
      #pragma unroll
      for (unsigned m = 0; m < 2; ++m)
        acc[m] = __builtin_amdgcn_mfma_f32_32x32x16_bf16(
                   ldfrag(wx_lds, rowA[m] + offw[w]), bo, acc[m], 0, 0, 0);
    }
    // relu + write h1 (col-major [b][k], swizzled, bf16 pairs)
    #pragma unroll
    for (unsigned m = 0; m < 2; ++m){
      relu16(acc[m]);
      #pragma unroll
      for (unsigned t = 0; t < 8; ++t){
        const unsigned k = rr_*64u + m*32u + 4u*hf + kpair[t];
        const unsigned byo = rowB + (((k>>3) ^ (l31 & 15u)) << 4) + (k & 7u)*2u;
        *(unsigned*)((char*)h1_lds + byo) = pk2c(acc[m][2u*t], acc[m][2u*t+1u]);
      }
    }
    __syncthreads();                                  // B1: h1 ready, wx reads done
    if (i + 1u < 128u) stage(wxp, wx_lds, i + 1u, wid, lane);

    // ---- L2: D2' = W1 * h1^T (+ b1 via K-ext) ----
    #pragma unroll
    for (unsigned m = 0; m < 2; ++m)
      acc[m] = __builtin_amdgcn_mfma_f32_32x32x16_bf16(w1f[m][8], frext, zero16(), 0, 0, 0);
    #pragma unroll
    for (unsigned w = 0; w < 8; ++w){
      const bf16x8 bh = ldfrag(h1_lds, rowB + offw[w]);
      #pragma unroll
      for (unsigned m = 0; m < 2; ++m)
        acc[m] = __builtin_amdgcn_mfma_f32_32x32x16_bf16(w1f[m][w], bh, acc[m], 0, 0, 0);
    }
    #pragma unroll
    for (unsigned m = 0; m < 2; ++m){
      relu16(acc[m]);
      #pragma unroll
      for (unsigned t = 0; t < 8; ++t){
        const unsigned k = rr_*64u + m*32u + 4u*hf + kpair[t];
        const unsigned byo = rowB + (((k>>3) ^ (l31 & 15u)) << 4) + (k & 7u)*2u;
        *(unsigned*)((char*)h2_lds + byo) = pk2c(acc[m][2u*t], acc[m][2u*t+1u]);
      }
    }
    __syncthreads();                                  // B2: h2 ready

    // ---- L3: D3' = W2 * h2^T (+ b2 via K-ext) ----
    #pragma unroll
    for (unsigned m = 0; m < 2; ++m)
      acc[m] = __builtin_amdgcn_mfma_f32_32x32x16_bf16(w2f[m][8], frext, zero16(), 0, 0, 0);
    #pragma unroll
    for (unsigned w = 0; w < 8; ++w){
      const bf16x8 bh = ldfrag(h2_lds, rowB + offw[w]);
      #pragma unroll
      for (unsigned m = 0; m < 2; ++m)
        acc[m] = __builtin_amdgcn_mfma_f32_32x32x16_bf16(w2f[m][w], bh, acc[m], 0, 0, 0);
    }

    // ---- epilogue: partial dot with Wf over this wave's 64 h-rows ----
    float s = 0.0f;
    #pragma unroll
    for (unsigned m = 0; m < 2; ++m){
      const float* wp = wf_s + (rr_*2u + m)*32u + hf*16u;
      float wv[16];
      *(float4*)&wv[0]  = *(const float4*)(wp);
      *(float4*)&wv[4]  = *(const float4*)(wp + 4);
      *(float4*)&wv[8]  = *(const float4*)(wp + 8);
      *(float4*)&wv[12] = *(const float4*)(wp + 12);
      #pragma unroll
      for (unsigned q = 0; q < 16; ++q) s += fmaxf(acc[m][q], 0.0f) * wv[q];
    }
    s += __shfl_xor(s, 32, 64);                       // combine hf halves
    if (hf == 0u) part_s[rr_*128u + bcol] = s;
    __syncthreads();                                  // Bp: partials ready
    if (rr_ == 0u && hf == 0u){
      const float o = part_s[bcol] + part_s[128u + bcol] + bfi;
      o_lds[bcol*128u + ((((i>>3) ^ (l31 & 15u)) << 3) | (i & 7u))] = bf16r(o);
      out[(size_t)(r0 + bcol)*128u + i] = o;
    }
    __syncthreads();                                  // B3: o updated, stage drained
  }
}

// ---------- host ----------
extern "C" void kernel_launch(void* const* d_in, const int* in_sizes, int n_in,
                              void* d_out, int out_size, void* d_ws, size_t ws_size,
                              hipStream_t stream) {
  (void)in_sizes; (void)n_in; (void)out_size;
  const float* x  = (const float*)d_in[0];
  const float* z  = (const float*)d_in[1];
  const float* M  = (const float*)d_in[2];
  const float* Wi = (const float*)d_in[3];
  const float* bi = (const float*)d_in[4];
  const float* Wf = (const float*)d_in[5];
  const float* bf = (const float*)d_in[6];
  const float* W1 = (const float*)d_in[7];
  const float* b1 = (const float*)d_in[8];
  const float* W2 = (const float*)d_in[9];
  const float* b2 = (const float*)d_in[10];
  float* out = (float*)d_out;

  // ws layout: wxp 4MB | ext_img 64KB | zT 32MB  (total ~36.1MB)
  char* ws = (char*)d_ws;
  unsigned short* wxp    = (unsigned short*)ws;
  unsigned*       extimg = (unsigned*)(ws + 4194304u);
  unsigned short* zTp    = (unsigned short*)(ws + 4194304u + 65536u);
  (void)ws_size; // requires ws_size >= 37,814,272 bytes

  prep_w<<<128, 256, 0, stream>>>(Wi, M, bi, wxp, extimg);
  prep_z<<<NROWS/64u, 256, 0, stream>>>(z, zTp);
  gen_main<<<NROWS/TM, 512, 0, stream>>>(x, Wf, bf, W1, b1, W2, b2,
                                         wxp, extimg, zTp, out);
}

// Round 6
// 1910.674 us; speedup vs baseline: 1.4350x; 1.2808x over previous
//
// R6 = R5 resubmitted (GPU acquisition failed; no evidence to act on).
// Desk audit this round: bank model recalibrated on R4 counters (b128 = 8
// lanes/phase -> XOR slot pattern conflict-free; retro-predicts both R4's
// clean reads AND the 4-way b32-write 2.03e8), frag-exchange slot algebra,
// buildfr order identical to R2-validated, race matrix incl. staging drains,
// VGPR ~230-250 vs 256 cap.
// Structure: in-register h handoff (buildfr) + b128 frag exchange: own 4
// k-windows stay in regs, partner-r half exchanged via h_lds as 4x
// ds_write_b128 + 4x ds_read_b128 per layer, slots ((s)^(l31&15))<<4.
// Weight slots [own0..3, partner0..3, bias] keep reg indices compile-time.
// LDS/wave/step: 32 b128 reads + 8 b128 writes (was 40 reads + 32 b32 4-way).
// Predicted: conflicts ~2e6, 1500-1900us, MfmaUtil 40-50%, WRITE_SIZE is the
// spill-vs-amplification discriminator.

#include <hip/hip_runtime.h>
#include <hip/hip_bf16.h>

typedef __bf16 bf16x8 __attribute__((ext_vector_type(8)));
typedef float  f32x16 __attribute__((ext_vector_type(16)));

#define AS1 __attribute__((address_space(1)))
#define AS3 __attribute__((address_space(3)))

#define NROWS 131072u
#define TM    128u

// ---------- helpers ----------
static __device__ __forceinline__ unsigned short bf16r(float x){ // RNE f32->bf16
  unsigned u = __builtin_bit_cast(unsigned, x);
  u = (u + 0x7FFFu + ((u >> 16) & 1u)) >> 16;
  return (unsigned short)u;
}
static __device__ __forceinline__ unsigned pk2c(float lo, float hi){
  unsigned d;
  asm("v_cvt_pk_bf16_f32 %0, %1, %2" : "=v"(d) : "v"(lo), "v"(hi));
  return d; // lo16 = bf16(lo), hi16 = bf16(hi)
}
static __device__ __forceinline__ bf16x8 mkfrag(unsigned a, unsigned b, unsigned c, unsigned d){
  uint4 t; t.x = a; t.y = b; t.z = c; t.w = d;
  return __builtin_bit_cast(bf16x8, t);
}
static __device__ __forceinline__ bf16x8 u4frag(const uint4 v){
  return __builtin_bit_cast(bf16x8, v);
}
static __device__ __forceinline__ bf16x8 ldfrag(const unsigned short* base, unsigned byteoff){
  const uint4 v = *(const uint4*)((const char*)base + byteoff);
  return __builtin_bit_cast(bf16x8, v);
}
static __device__ __forceinline__ f32x16 zero16(){
  f32x16 v;
  #pragma unroll
  for (int j = 0; j < 16; ++j) v[j] = 0.0f;
  return v;
}
static __device__ __forceinline__ void relu16(f32x16& a){
  #pragma unroll
  for (int j = 0; j < 16; ++j) a[j] = fmaxf(a[j], 0.0f);
}
// Pack a relu'd 32x32 acc tile into next-layer B-frags (R2-hardware-validated).
// D-layout col=lane&31, row nu=(r&3)+8*(r>>2)+4*(lane>>5). Output: lo = frag
// for the tile's first 16-k window, hi = second, each 4 dwords at own
// (l31,hf) position.
static __device__ __forceinline__ void buildfr(const f32x16& a, uint4& lo, uint4& hi){
  unsigned p0 = pk2c(a[0],a[1]),  p1 = pk2c(a[2],a[3]);
  unsigned p2 = pk2c(a[4],a[5]),  p3 = pk2c(a[6],a[7]);
  unsigned q0 = pk2c(a[8],a[9]),  q1 = pk2c(a[10],a[11]);
  unsigned q2 = pk2c(a[12],a[13]),q3 = pk2c(a[14],a[15]);
  { auto r = __builtin_amdgcn_permlane32_swap(p0, p2, false, false); lo.x=r[0]; lo.z=r[1]; }
  { auto r = __builtin_amdgcn_permlane32_swap(p1, p3, false, false); lo.y=r[0]; lo.w=r[1]; }
  { auto r = __builtin_amdgcn_permlane32_swap(q0, q2, false, false); hi.x=r[0]; hi.z=r[1]; }
  { auto r = __builtin_amdgcn_permlane32_swap(q1, q3, false, false); hi.y=r[0]; hi.w=r[1]; }
}
// Stage the 32KB pre-swizzled Wx image for step i into LDS (linear copy, 8 waves).
static __device__ __forceinline__ void stage(const unsigned short* __restrict__ wxp,
                                             unsigned short* wx_lds,
                                             unsigned i, unsigned wid, unsigned lane){
  const char* src = (const char*)wxp + (size_t)i*32768u + wid*4096u + lane*16u;
  char* dst = (char*)wx_lds + wid*4096u;            // wave-uniform base; HW adds lane*16
  #pragma unroll
  for (unsigned c = 0; c < 4; ++c)
    __builtin_amdgcn_global_load_lds((const AS1 unsigned*)(src + c*1024u),
                                     (AS3 unsigned*)(dst + c*1024u), 16, 0, 0);
}

// ---------- prep kernels (unchanged, validated) ----------
__global__ __launch_bounds__(256) void prep_w(const float* __restrict__ Wi,
                                              const float* __restrict__ M,
                                              const float* __restrict__ bi,
                                              unsigned short* __restrict__ wxp,
                                              unsigned* __restrict__ extimg){
  const unsigned i = blockIdx.x, tid = threadIdx.x;
  __shared__ float mcol[128];
  if (tid < 128u) mcol[tid] = (tid == i) ? 0.0f : M[tid*128u + i];
  __syncthreads();
  const float* wrow = Wi + (size_t)i*128u*129u;
  unsigned short* dst = wxp + (size_t)i*16384u;
  #pragma unroll 4
  for (unsigned p = 0; p < 64; ++p){
    unsigned e = p*256u + tid;
    unsigned hh = e >> 7, j = e & 127u;
    float v = wrow[hh*129u + j] * mcol[j];
    dst[hh*128u + ((((j>>3) ^ (hh & 15u)) << 3) | (j & 7u))] = bf16r(v);
  }
  if (tid < 128u){
    float wz = wrow[tid*129u + 128u];
    float bv = bi[i*128u + tid];
    extimg[i*128u + tid] = (unsigned)bf16r(wz) | ((unsigned)bf16r(bv) << 16);
  }
}
__global__ __launch_bounds__(256) void prep_z(const float* __restrict__ z,
                                              unsigned short* __restrict__ zT){
  __shared__ float t[64][129];
  const unsigned tid = threadIdx.x, b0 = blockIdx.x * 64u;
  #pragma unroll 4
  for (unsigned p = 0; p < 32; ++p){
    unsigned e = p*256u + tid;
    t[e >> 7][e & 127u] = z[(size_t)b0*128u + e];
  }
  __syncthreads();
  #pragma unroll 4
  for (unsigned p = 0; p < 32; ++p){
    unsigned e = p*256u + tid;
    unsigned ii = e >> 6, bb = e & 63u;
    zT[(size_t)ii*NROWS + b0 + bb] = bf16r(t[bb][ii]);
  }
}

// ---------- main persistent scan kernel ----------
__global__ __launch_bounds__(512, 2) void gen_main(
    const float* __restrict__ x,   const float* __restrict__ Wf,
    const float* __restrict__ bfp, const float* __restrict__ W1,
    const float* __restrict__ b1,  const float* __restrict__ W2,
    const float* __restrict__ b2,  const unsigned short* __restrict__ wxp,
    const unsigned* __restrict__ extimg, const unsigned short* __restrict__ zT,
    float* __restrict__ out)
{
  __shared__ unsigned short o_lds[16384];   // out state [b][j], bf16, swizzled
  __shared__ unsigned short wx_lds[16384];  // per-step Wx image
  __shared__ unsigned short h1_lds[16384];  // B-frag slots [b][s], s = k>>3
  __shared__ unsigned short h2_lds[16384];  // B-frag slots [b][s]
  __shared__ float wf_s[128];               // Wf[i] in [mu][hf][reg] order
  __shared__ float part_s[256];             // [r][b] epilogue partials

  const unsigned tid  = threadIdx.x;
  const unsigned wid  = tid >> 6, lane = tid & 63u;
  const unsigned l31  = lane & 31u, hf = lane >> 5;
  const unsigned rr_  = wid >> 2, cc_ = wid & 3u;   // h-row pair / batch-col group
  const unsigned r0   = blockIdx.x * TM;
  const unsigned bcol = cc_*32u + l31;              // owned batch row/col

  // o_lds <- bf16(x) (swizzled)
  #pragma unroll 4
  for (unsigned p = 0; p < 32; ++p){
    unsigned e = p*512u + tid;
    unsigned row = e >> 7, col = e & 127u;
    float v = x[(size_t)r0*128u + e];
    o_lds[row*128u + ((((col>>3) ^ (row & 15u)) << 3) | (col & 7u))] = bf16r(v);
  }

  // Weight A-frag slots ordered by ownership: slot j<4 -> window 4rr_+j,
  // slot 4+j -> window 4(1-rr_)+j, slot 8 -> K-ext bias frag. All loop
  // indices over slots are compile-time (rule 20); window is uniform-runtime.
  bf16x8 w1f[2][9], w2f[2][9];
  #pragma unroll
  for (unsigned m = 0; m < 2; ++m){
    const unsigned row = rr_*64u + m*32u + l31;
    #pragma unroll
    for (unsigned j = 0; j < 8; ++j){
      const unsigned w = (j < 4u) ? (rr_*4u + j) : ((1u-rr_)*4u + (j-4u));
      const float4 a0 = *(const float4*)(W1 + row*128u + w*16u + hf*8u);
      const float4 a1 = *(const float4*)(W1 + row*128u + w*16u + hf*8u + 4u);
      w1f[m][j] = mkfrag(pk2c(a0.x,a0.y), pk2c(a0.z,a0.w), pk2c(a1.x,a1.y), pk2c(a1.z,a1.w));
      const float4 c0 = *(const float4*)(W2 + row*128u + w*16u + hf*8u);
      const float4 c1 = *(const float4*)(W2 + row*128u + w*16u + hf*8u + 4u);
      w2f[m][j] = mkfrag(pk2c(c0.x,c0.y), pk2c(c0.z,c0.w), pk2c(c1.x,c1.y), pk2c(c1.z,c1.w));
    }
    w1f[m][8] = mkfrag(hf==0u ? (unsigned)bf16r(b1[row]) : 0u, 0u, 0u, 0u);
    w2f[m][8] = mkfrag(hf==0u ? (unsigned)bf16r(b2[row]) : 0u, 0u, 0u, 0u);
  }
  const bf16x8 frext = mkfrag(hf==0u ? 0x00003F80u : 0u, 0u, 0u, 0u); // act=1.0 @k-ext

  // L1 read offsets (proven pattern), h-exchange offsets (same pattern)
  unsigned offw[8];
  #pragma unroll
  for (unsigned w = 0; w < 8; ++w) offw[w] = ((2u*w + hf) ^ (l31 & 15u)) << 4;
  unsigned rowA[2];
  #pragma unroll
  for (unsigned m = 0; m < 2; ++m) rowA[m] = (rr_*64u + m*32u + l31) * 256u;
  const unsigned rowB = bcol * 256u;
  unsigned ow_off[4], part_off[4];   // own-write / partner-read slot offsets
  #pragma unroll
  for (unsigned j = 0; j < 4; ++j){
    ow_off[j]   = (((8u*rr_        + 2u*j + hf) ^ (l31 & 15u)) << 4);
    part_off[j] = (((8u*(1u-rr_)   + 2u*j + hf) ^ (l31 & 15u)) << 4);
  }

  stage(wxp, wx_lds, 0u, wid, lane);
  __syncthreads();

  #pragma unroll 1
  for (unsigned i = 0; i < 128u; ++i){
    if (tid < 128u){ // Wf[i] -> [mu][hf][reg] table (read post-L3; B1/B2 intervene)
      unsigned mu = tid >> 5, rem = tid & 31u;
      unsigned hfv = (rem >> 2) & 1u, rg = (rem & 3u) | ((rem >> 3) << 2);
      wf_s[mu*32u + hfv*16u + rg] = Wf[i*128u + tid];
    }
    const unsigned short zb = zT[(size_t)i*NROWS + r0 + bcol];
    const unsigned eB = (hf == 0u) ? ((unsigned)zb | 0x3F800000u) : 0u;   // {z, 1.0}
    unsigned ea[2];
    #pragma unroll
    for (unsigned m = 0; m < 2; ++m)
      ea[m] = (hf == 0u) ? extimg[i*128u + rr_*64u + m*32u + l31] : 0u;   // {wz, bi}
    const float bfi = bfp[i];

    // ---- L1: D1'[h][b] = Wx' * out^T (+ z*wz + bi via K-ext) ----
    f32x16 acc[2];
    {
      const bf16x8 be = mkfrag(eB, 0u, 0u, 0u);
      #pragma unroll
      for (unsigned m = 0; m < 2; ++m)
        acc[m] = __builtin_amdgcn_mfma_f32_32x32x16_bf16(
                   mkfrag(ea[m],0u,0u,0u), be, zero16(), 0, 0, 0);
    }
    #pragma unroll
    for (unsigned w = 0; w < 8; ++w){
      const bf16x8 bo = ldfrag(o_lds, rowB + offw[w]);
      #pragma unroll
      for (unsigned m = 0; m < 2; ++m)
        acc[m] = __builtin_amdgcn_mfma_f32_32x32x16_bf16(
                   ldfrag(wx_lds, rowA[m] + offw[w]), bo, acc[m], 0, 0, 0);
    }
    // relu + pack own B-frags in-register; export own half to h1_lds (b128)
    uint4 f1[2][2];
    #pragma unroll
    for (unsigned m = 0; m < 2; ++m){
      relu16(acc[m]);
      buildfr(acc[m], f1[m][0], f1[m][1]);
      *(uint4*)((char*)h1_lds + rowB + ow_off[2u*m+0u]) = f1[m][0];
      *(uint4*)((char*)h1_lds + rowB + ow_off[2u*m+1u]) = f1[m][1];
    }
    __syncthreads();                                  // B1: h1 ready, wx reads done
    if (i + 1u < 128u) stage(wxp, wx_lds, i + 1u, wid, lane);

    // ---- L2: D2' = W1 * h1^T (+ b1 via K-ext) ----
    #pragma unroll
    for (unsigned m = 0; m < 2; ++m)
      acc[m] = __builtin_amdgcn_mfma_f32_32x32x16_bf16(w1f[m][8], frext, zero16(), 0, 0, 0);
    #pragma unroll
    for (unsigned j = 0; j < 4; ++j){                 // own windows (regs)
      const bf16x8 bb = u4frag(f1[j>>1][j&1]);
      #pragma unroll
      for (unsigned m = 0; m < 2; ++m)
        acc[m] = __builtin_amdgcn_mfma_f32_32x32x16_bf16(w1f[m][j], bb, acc[m], 0, 0, 0);
    }
    #pragma unroll
    for (unsigned j = 0; j < 4; ++j){                 // partner windows (LDS)
      const bf16x8 bb = ldfrag(h1_lds, rowB + part_off[j]);
      #pragma unroll
      for (unsigned m = 0; m < 2; ++m)
        acc[m] = __builtin_amdgcn_mfma_f32_32x32x16_bf16(w1f[m][4u+j], bb, acc[m], 0, 0, 0);
    }
    uint4 f2[2][2];
    #pragma unroll
    for (unsigned m = 0; m < 2; ++m){
      relu16(acc[m]);
      buildfr(acc[m], f2[m][0], f2[m][1]);
      *(uint4*)((char*)h2_lds + rowB + ow_off[2u*m+0u]) = f2[m][0];
      *(uint4*)((char*)h2_lds + rowB + ow_off[2u*m+1u]) = f2[m][1];
    }
    __syncthreads();                                  // B2: h2 ready (+wx landed)

    // ---- L3: D3' = W2 * h2^T (+ b2 via K-ext) ----
    #pragma unroll
    for (unsigned m = 0; m < 2; ++m)
      acc[m] = __builtin_amdgcn_mfma_f32_32x32x16_bf16(w2f[m][8], frext, zero16(), 0, 0, 0);
    #pragma unroll
    for (unsigned j = 0; j < 4; ++j){
      const bf16x8 bb = u4frag(f2[j>>1][j&1]);
      #pragma unroll
      for (unsigned m = 0; m < 2; ++m)
        acc[m] = __builtin_amdgcn_mfma_f32_32x32x16_bf16(w2f[m][j], bb, acc[m], 0, 0, 0);
    }
    #pragma unroll
    for (unsigned j = 0; j < 4; ++j){
      const bf16x8 bb = ldfrag(h2_lds, rowB + part_off[j]);
      #pragma unroll
      for (unsigned m = 0; m < 2; ++m)
        acc[m] = __builtin_amdgcn_mfma_f32_32x32x16_bf16(w2f[m][4u+j], bb, acc[m], 0, 0, 0);
    }

    // ---- epilogue: partial dot with Wf over this wave's 64 h-rows ----
    float s = 0.0f;
    #pragma unroll
    for (unsigned m = 0; m < 2; ++m){
      const float* wp = wf_s + (rr_*2u + m)*32u + hf*16u;
      float wv[16];
      *(float4*)&wv[0]  = *(const float4*)(wp);
      *(float4*)&wv[4]  = *(const float4*)(wp + 4);
      *(float4*)&wv[8]  = *(const float4*)(wp + 8);
      *(float4*)&wv[12] = *(const float4*)(wp + 12);
      #pragma unroll
      for (unsigned q = 0; q < 16; ++q) s += fmaxf(acc[m][q], 0.0f) * wv[q];
    }
    s += __shfl_xor(s, 32, 64);                       // combine hf halves
    if (hf == 0u) part_s[rr_*128u + bcol] = s;
    __syncthreads();                                  // Bp: partials ready
    if (rr_ == 0u && hf == 0u){
      const float o = part_s[bcol] + part_s[128u + bcol] + bfi;
      o_lds[bcol*128u + ((((i>>3) ^ (l31 & 15u)) << 3) | (i & 7u))] = bf16r(o);
      out[(size_t)(r0 + bcol)*128u + i] = o;
    }
    __syncthreads();                                  // B3: o updated
  }
}

// ---------- host ----------
extern "C" void kernel_launch(void* const* d_in, const int* in_sizes, int n_in,
                              void* d_out, int out_size, void* d_ws, size_t ws_size,
                              hipStream_t stream) {
  (void)in_sizes; (void)n_in; (void)out_size;
  const float* x  = (const float*)d_in[0];
  const float* z  = (const float*)d_in[1];
  const float* M  = (const float*)d_in[2];
  const float* Wi = (const float*)d_in[3];
  const float* bi = (const float*)d_in[4];
  const float* Wf = (const float*)d_in[5];
  const float* bf = (const float*)d_in[6];
  const float* W1 = (const float*)d_in[7];
  const float* b1 = (const float*)d_in[8];
  const float* W2 = (const float*)d_in[9];
  const float* b2 = (const float*)d_in[10];
  float* out = (float*)d_out;

  // ws layout: wxp 4MB | ext_img 64KB | zT 32MB  (total ~36.1MB)
  char* ws = (char*)d_ws;
  unsigned short* wxp    = (unsigned short*)ws;
  unsigned*       extimg = (unsigned*)(ws + 4194304u);
  unsigned short* zTp    = (unsigned short*)(ws + 4194304u + 65536u);
  (void)ws_size; // requires ws_size >= 37,814,272 bytes

  prep_w<<<128, 256, 0, stream>>>(Wi, M, bi, wxp, extimg);
  prep_z<<<NROWS/64u, 256, 0, stream>>>(z, zTp);
  gen_main<<<NROWS/TM, 512, 0, stream>>>(x, Wf, bf, W1, b1, W2, b2,
                                         wxp, extimg, zTp, out);
}